// Round 1
// baseline (242760.132 us; speedup 1.0000x reference)
//
#include <hip/hip_runtime.h>

#define NBLK 256
#define NTHR 256
#define BH   (64*512)

__device__ __forceinline__ float sigm(float x){ return 1.f/(1.f+__expf(-x)); }
// stable tanh: no inf/inf
__device__ __forceinline__ float tanh_(float x){ return 1.f - 2.f/(__expf(2.f*x)+1.f); }

__device__ __forceinline__ float wred_max(float v){
  #pragma unroll
  for (int off=32; off; off>>=1) v = fmaxf(v, __shfl_xor(v, off, 64));
  return v;
}
__device__ __forceinline__ float wred_sum(float v){
  #pragma unroll
  for (int off=32; off; off>>=1) v += __shfl_xor(v, off, 64);
  return v;
}

// generation-based grid barrier; requires all NBLK blocks co-resident
// (256 blocks x 256 thr, <=9KB LDS -> always true on 256 CUs)
__device__ __forceinline__ void gsync(unsigned* cnt, unsigned* gen){
  __threadfence();
  __syncthreads();
  if (threadIdx.x == 0){
    unsigned g   = __hip_atomic_load(gen, __ATOMIC_RELAXED, __HIP_MEMORY_SCOPE_AGENT);
    unsigned old = __hip_atomic_fetch_add(cnt, 1u, __ATOMIC_ACQ_REL, __HIP_MEMORY_SCOPE_AGENT);
    if (old == (unsigned)(NBLK-1)){
      __hip_atomic_store(cnt, 0u,  __ATOMIC_RELAXED, __HIP_MEMORY_SCOPE_AGENT);
      __hip_atomic_store(gen, g+1u, __ATOMIC_RELEASE, __HIP_MEMORY_SCOPE_AGENT);
    } else {
      while (__hip_atomic_load(gen, __ATOMIC_ACQUIRE, __HIP_MEMORY_SCOPE_AGENT) == g)
        __builtin_amdgcn_s_sleep(2);
    }
  }
  __syncthreads();
  __threadfence();
}

// acc two dot products (same W row, two input rows), 4 independent chains each
__device__ __forceinline__ void dotacc(const float* __restrict__ wrow,
                                       const float* __restrict__ x0,
                                       const float* __restrict__ x1,
                                       const int len, float4& a0, float4& a1){
  #pragma unroll 4
  for (int k=0; k<len; k+=4){
    const float4 wv = *(const float4*)(wrow+k);
    const float4 u0 = *(const float4*)(x0+k);
    const float4 u1 = *(const float4*)(x1+k);
    a0.x = fmaf(wv.x,u0.x,a0.x); a0.y = fmaf(wv.y,u0.y,a0.y);
    a0.z = fmaf(wv.z,u0.z,a0.z); a0.w = fmaf(wv.w,u0.w,a0.w);
    a1.x = fmaf(wv.x,u1.x,a1.x); a1.y = fmaf(wv.y,u1.y,a1.y);
    a1.z = fmaf(wv.z,u1.z,a1.z); a1.w = fmaf(wv.w,u1.w,a1.w);
  }
}

// One LSTM layer phase. Grid covers [4 b-tiles x 64 j-quads]; WG tile = 16 b x 8 j' x 4 gates.
// Thread = one W row (gate,j') x 2 batch rows. Cell update via LDS gate exchange.
template<bool L0>
__device__ __forceinline__ void lstm_phase(
    int w, int tid, int t,
    const float* __restrict__ Wih, const float* __restrict__ Whh, const float* __restrict__ bias,
    const float* __restrict__ tgt,      // layer0 only: padded_targets [64][256][80]
    const float* __restrict__ in1,      // layer0: CTX[64][512]; else h_{l-1} (new parity)
    const float* __restrict__ hprev,    // h_l old parity [64][512]
    float* __restrict__ hout,           // h_l new parity
    float* __restrict__ cbuf,           // c_l [64][512]
    float* __restrict__ sgate)          // LDS [16][8][4]
{
  const int bt   = w >> 6;            // 0..3   (16 b each)
  const int rq   = w & 63;            // 0..63  (8 j' each)
  const int row  = tid & 31;          // 0..31
  const int bp   = tid >> 5;          // 0..7
  const int jloc = row & 7;
  const int gate = row >> 3;
  const int b0   = (bt<<4) | (bp<<1), b1 = b0 | 1;
  const int jp   = (rq<<3) | jloc;          // 0..511
  const int wrow = (gate<<9) | jp;          // 0..2047

  float4 a0 = {bias[wrow],0.f,0.f,0.f};
  float4 a1 = {bias[wrow],0.f,0.f,0.f};

  if (L0){
    const float* wi = Wih + wrow*592;
    dotacc(wi,     tgt + (b0*256 + t)*80, tgt + (b1*256 + t)*80, 80,  a0, a1);
    dotacc(wi+80,  in1 + (b0<<9),         in1 + (b1<<9),         512, a0, a1);
  } else {
    const float* wi = Wih + (wrow<<9);
    dotacc(wi,     in1 + (b0<<9),         in1 + (b1<<9),         512, a0, a1);
  }
  dotacc(Whh + (wrow<<9), hprev + (b0<<9), hprev + (b1<<9), 512, a0, a1);

  const float d0 = (a0.x+a0.y)+(a0.z+a0.w);
  const float d1 = (a1.x+a1.y)+(a1.z+a1.w);
  sgate[(((bp<<1)  )*8 + jloc)*4 + gate] = d0;
  sgate[(((bp<<1)|1)*8 + jloc)*4 + gate] = d1;
  __syncthreads();

  if (tid < 128){
    const int bl = tid >> 3, jl2 = tid & 7;
    const float* gq = &sgate[(bl*8 + jl2)*4];
    const float gi = sigm (gq[0]);
    const float gf = sigm (gq[1]);
    const float gg = tanh_(gq[2]);
    const float go = sigm (gq[3]);
    const int b = (bt<<4) + bl;
    const int j = (rq<<3) + jl2;
    const int idx = (b<<9) + j;
    const float cn = gf*cbuf[idx] + gi*gg;
    cbuf[idx] = cn;
    hout[idx] = go * tanh_(cn);
  }
  __syncthreads();
}

// Attention + FC for one batch row (WG w = b). 256 threads.
__device__ __forceinline__ void attn_phase(
    int b, int tid, int t,
    const float* __restrict__ enc, const int* __restrict__ lens,
    const float* __restrict__ Wq,  const float* __restrict__ Wfc, const float* __restrict__ bfc,
    const float* __restrict__ h2,  float* __restrict__ ctx,
    float* __restrict__ out, float* __restrict__ sh)
{
  float* sh_h = sh;          // 512: h2, later ctx
  float* sh_q = sh + 512;    // 512: q, later pred partials
  float* sh_s = sh + 1024;   // 512: scores -> softmax weights
  float* red  = sh + 1536;   // 16

  const float* hb = h2 + (b<<9);
  for (int k=tid; k<512; k+=NTHR) sh_h[k] = hb[k];
  __syncthreads();

  // q = h2 @ Wq  (Wq [512,512] row-major, k-major reads, coalesced over tid)
  {
    float q0=0.f,q1=0.f,q2=0.f,q3=0.f;
    for (int k=0;k<512;k+=2){
      const float h0 = sh_h[k], h1 = sh_h[k+1];
      const float* wq = Wq + (k<<9);
      q0 = fmaf(h0, wq[tid],         q0);
      q1 = fmaf(h0, wq[tid+256],     q1);
      q2 = fmaf(h1, wq[512+tid],     q2);
      q3 = fmaf(h1, wq[512+tid+256], q3);
    }
    sh_q[tid]     = q0+q2;
    sh_q[tid+256] = q1+q3;
  }
  __syncthreads();

  const int len = lens[b];
  const float scale = 0.04419417382415922f;   // 1/sqrt(512)
  float p0, p1, inv;
  {
    // scores: thread handles s = tid and tid+256, row-contiguous float4 reads
    const float* e0p = enc + ((size_t)b*512 + tid)*512;
    const float* e1p = e0p + 256*512;
    float4 a0 = {0,0,0,0}, a1 = {0,0,0,0};
    #pragma unroll 2
    for (int k=0;k<512;k+=4){
      const float4 qv = *(const float4*)(sh_q+k);
      const float4 v0 = *(const float4*)(e0p+k);
      const float4 v1 = *(const float4*)(e1p+k);
      a0.x=fmaf(qv.x,v0.x,a0.x); a0.y=fmaf(qv.y,v0.y,a0.y);
      a0.z=fmaf(qv.z,v0.z,a0.z); a0.w=fmaf(qv.w,v0.w,a0.w);
      a1.x=fmaf(qv.x,v1.x,a1.x); a1.y=fmaf(qv.y,v1.y,a1.y);
      a1.z=fmaf(qv.z,v1.z,a1.z); a1.w=fmaf(qv.w,v1.w,a1.w);
    }
    float s0 = ((a0.x+a0.y)+(a0.z+a0.w))*scale + ((tid      < len) ? 0.f : -1e9f);
    float s1 = ((a1.x+a1.y)+(a1.z+a1.w))*scale + ((tid+256  < len) ? 0.f : -1e9f);
    // softmax
    float m = wred_max(fmaxf(s0,s1));
    if ((tid&63)==0) red[tid>>6] = m;
    __syncthreads();
    m = fmaxf(fmaxf(red[0],red[1]), fmaxf(red[2],red[3]));
    p0 = __expf(s0-m); p1 = __expf(s1-m);
    float ssum = wred_sum(p0+p1);
    if ((tid&63)==0) red[8+(tid>>6)] = ssum;
    __syncthreads();
    inv = 1.f/((red[8]+red[9])+(red[10]+red[11]));
    sh_s[tid]     = p0*inv;
    sh_s[tid+256] = p1*inv;
  }
  __syncthreads();

  // ctx = w @ enc  (column access: coalesced over tid at each s)
  {
    float c0=0.f,c1=0.f,c2=0.f,c3=0.f;
    const float* eb = enc + (size_t)b*512*512;
    for (int s=0;s<512;s+=2){
      const float w0 = sh_s[s], w1 = sh_s[s+1];
      const float* r0 = eb + (s<<9);
      c0 = fmaf(w0, r0[tid],         c0);
      c1 = fmaf(w0, r0[tid+256],     c1);
      c2 = fmaf(w1, r0[512+tid],     c2);
      c3 = fmaf(w1, r0[512+tid+256], c3);
    }
    c0 += c2; c1 += c3;
    ctx[(b<<9)+tid]     = c0;
    ctx[(b<<9)+tid+256] = c1;
    sh_h[tid] = c0; sh_h[tid+256] = c1;   // reuse as ctx in LDS
  }
  __syncthreads();

  // pred = ctx @ Wfc + bfc   (Wfc [512,80]); 240 threads = 80 f x 3 e-segments
  if (tid < 240){
    const int seg = (tid >= 160) ? 2 : (tid >= 80 ? 1 : 0);
    const int f   = tid - seg*80;
    const int e0  = seg*171;
    const int e1  = (seg==2) ? 512 : e0+171;
    float acc = 0.f;
    for (int e=e0; e<e1; ++e) acc = fmaf(sh_h[e], Wfc[e*80+f], acc);
    sh_q[tid] = acc;
  }
  __syncthreads();
  if (tid < 80){
    out[((size_t)b*255 + t)*80 + tid] = sh_q[tid] + sh_q[tid+80] + sh_q[tid+160] + bfc[tid];
  }
}

__global__ __launch_bounds__(NTHR, 1)
void sd_kernel(const float* __restrict__ tgt,  const float* __restrict__ enc,
               const int*   __restrict__ lens,
               const float* __restrict__ Wih0, const float* __restrict__ Whh0, const float* __restrict__ b0,
               const float* __restrict__ Wih1, const float* __restrict__ Whh1, const float* __restrict__ b1,
               const float* __restrict__ Wih2, const float* __restrict__ Whh2, const float* __restrict__ b2,
               const float* __restrict__ Wq,   const float* __restrict__ Wfc,  const float* __restrict__ bfc,
               float* __restrict__ out, void* __restrict__ wsv)
{
  unsigned* cnt = (unsigned*)wsv;
  unsigned* gen = cnt + 1;
  float* ws  = (float*)((char*)wsv + 256);
  float* H   = ws;            // [3 layers][2 parity][64][512]
  float* C   = H + 3*2*BH;    // [3][64][512]
  float* CTX = C + 3*BH;      // [64][512]

  const int w = blockIdx.x, tid = threadIdx.x;

  __shared__ __attribute__((aligned(16))) float sgate[512];
  __shared__ __attribute__((aligned(16))) float sh[1552];

  // zero-init state every call (ws is poisoned once; harness never re-poisons)
  for (int i = w*NTHR + tid; i < 10*BH; i += NBLK*NTHR) ws[i] = 0.f;
  gsync(cnt, gen);

  for (int t=0; t<255; ++t){
    const int p = t & 1, np = p ^ 1;
    lstm_phase<true >(w,tid,t, Wih0,Whh0,b0, tgt,    CTX,            H+(0*2+p)*BH, H+(0*2+np)*BH, C+0*BH, sgate);
    gsync(cnt,gen);
    lstm_phase<false>(w,tid,t, Wih1,Whh1,b1, nullptr, H+(0*2+np)*BH, H+(1*2+p)*BH, H+(1*2+np)*BH, C+1*BH, sgate);
    gsync(cnt,gen);
    lstm_phase<false>(w,tid,t, Wih2,Whh2,b2, nullptr, H+(1*2+np)*BH, H+(2*2+p)*BH, H+(2*2+np)*BH, C+2*BH, sgate);
    gsync(cnt,gen);
    if (w < 64)
      attn_phase(w,tid,t, enc,lens,Wq,Wfc,bfc, H+(2*2+np)*BH, CTX, out, sh);
    gsync(cnt,gen);
  }
}

extern "C" void kernel_launch(void* const* d_in, const int* in_sizes, int n_in,
                              void* d_out, int out_size, void* d_ws, size_t ws_size,
                              hipStream_t stream) {
  const float* tgt  = (const float*)d_in[0];
  const float* enc  = (const float*)d_in[1];
  const int*   lens = (const int*)  d_in[2];
  const float* Wih0 = (const float*)d_in[3];
  const float* Whh0 = (const float*)d_in[4];
  const float* b0   = (const float*)d_in[5];
  const float* Wih1 = (const float*)d_in[6];
  const float* Whh1 = (const float*)d_in[7];
  const float* b1   = (const float*)d_in[8];
  const float* Wih2 = (const float*)d_in[9];
  const float* Whh2 = (const float*)d_in[10];
  const float* b2   = (const float*)d_in[11];
  const float* Wq   = (const float*)d_in[12];
  const float* Wfc  = (const float*)d_in[13];
  const float* bfc  = (const float*)d_in[14];

  // barrier counters live at ws[0:256] — must be zeroed every call (capture-safe)
  hipMemsetAsync(d_ws, 0, 256, stream);
  sd_kernel<<<NBLK, NTHR, 0, stream>>>(tgt, enc, lens,
                                       Wih0, Whh0, b0,
                                       Wih1, Whh1, b1,
                                       Wih2, Whh2, b2,
                                       Wq, Wfc, bfc,
                                       (float*)d_out, d_ws);
}

// Round 2
// 238027.124 us; speedup vs baseline: 1.0199x; 1.0199x over previous
//
#include <hip/hip_runtime.h>

#define NBLK 256
#define NTHR 512

// ---------------- math helpers ----------------
__device__ __forceinline__ float sigm(float x){ return 1.f/(1.f+__expf(-x)); }
__device__ __forceinline__ float tanh_(float x){ return 1.f - 2.f/(__expf(2.f*x)+1.f); }

__device__ __forceinline__ float wred_max(float v){
  #pragma unroll
  for (int off=32; off; off>>=1) v = fmaxf(v, __shfl_xor(v, off, 64));
  return v;
}
__device__ __forceinline__ float wred_sum(float v){
  #pragma unroll
  for (int off=32; off; off>>=1) v += __shfl_xor(v, off, 64);
  return v;
}

// generation-based grid barrier; all NBLK blocks co-resident (1 WG/CU)
__device__ __forceinline__ void gsync(unsigned* cnt, unsigned* gen){
  __threadfence();
  __syncthreads();
  if (threadIdx.x == 0){
    unsigned g   = __hip_atomic_load(gen, __ATOMIC_RELAXED, __HIP_MEMORY_SCOPE_AGENT);
    unsigned old = __hip_atomic_fetch_add(cnt, 1u, __ATOMIC_ACQ_REL, __HIP_MEMORY_SCOPE_AGENT);
    if (old == (unsigned)(NBLK-1)){
      __hip_atomic_store(cnt, 0u,  __ATOMIC_RELAXED, __HIP_MEMORY_SCOPE_AGENT);
      __hip_atomic_store(gen, g+1u, __ATOMIC_RELEASE, __HIP_MEMORY_SCOPE_AGENT);
    } else {
      while (__hip_atomic_load(gen, __ATOMIC_ACQUIRE, __HIP_MEMORY_SCOPE_AGENT) == g)
        __builtin_amdgcn_s_sleep(2);
    }
  }
  __syncthreads();
  __threadfence();
}

// ---------------- LSTM layer phase ----------------
// WG owns 8 rows = 2 j's x 4 gates of the [2048 x K] gate matrix.
// thread (r = tid>>6, s = tid&63) holds W[row][i*256 + s*4 + j] in registers.
// Inputs read coalesced from global (hot L2 state buffers).
template<int NI>
__device__ __forceinline__ void lstm_layer(
    int w, int tid, const float (&wt)[NI][4], float breg,
    const float* __restrict__ in, int instride,
    float* __restrict__ cbuf,
    float* __restrict__ dstA, int strA,
    float* __restrict__ dstB, int strB,
    float* sPart, float* sG4)
{
  const int s = tid & 63;
  const int j0 = w << 1;
  const int r  = tid >> 6;

  #pragma unroll 1
  for (int ch=0; ch<8; ++ch){
    float p[8];
    #pragma unroll
    for (int bb=0; bb<8; ++bb){
      const float* row = in + ((ch<<3)+bb)*instride + (s<<2);
      float a0=0.f,a1=0.f,a2=0.f,a3=0.f;
      #pragma unroll
      for (int i=0;i<NI;++i){
        const float4 x = *(const float4*)(row + (i<<8));
        a0 = fmaf(wt[i][0], x.x, a0);
        a1 = fmaf(wt[i][1], x.y, a1);
        a2 = fmaf(wt[i][2], x.z, a2);
        a3 = fmaf(wt[i][3], x.w, a3);
      }
      p[bb] = (a0+a1)+(a2+a3);
    }
    __syncthreads();                       // sPart free (prev reduce done)
    #pragma unroll
    for (int bb=0; bb<8; ++bb)
      sPart[((((bb<<3)|r)<<6) | s)] = p[bb];
    __syncthreads();
    {
      const int seg = tid & 7, r2 = (tid>>3)&7, bb2 = tid>>6;
      const float* pp = sPart + (((bb2<<3)|r2)<<6) + (seg<<3);
      float v = ((pp[0]+pp[1])+(pp[2]+pp[3])) + ((pp[4]+pp[5])+(pp[6]+pp[7]));
      v += __shfl_xor(v,1,64);
      v += __shfl_xor(v,2,64);
      v += __shfl_xor(v,4,64);
      if (seg==0) sG4[(bb2<<3)|r2] = v + breg;
    }
    __syncthreads();
    if (tid < 16){
      const int bb = tid>>1, jl = tid&1;
      const int b = (ch<<3) + bb;
      const float gi = sigm (sG4[(bb<<3) + (jl<<2) + 0]);
      const float gf = sigm (sG4[(bb<<3) + (jl<<2) + 1]);
      const float gg = tanh_(sG4[(bb<<3) + (jl<<2) + 2]);
      const float go = sigm (sG4[(bb<<3) + (jl<<2) + 3]);
      const int j  = j0 + jl;
      const int ci = (b<<9) + j;
      const float cn = gf*cbuf[ci] + gi*gg;
      cbuf[ci] = cn;
      const float hn = go * tanh_(cn);
      dstA[b*strA + j] = hn;
      dstB[b*strB + j] = hn;
    }
  }
}

// ws float offsets (after 256B barrier area)
#define IN0_OFF   0            // [2][64][1280]  layout per row: [ctx 0:512][h0 512:1024][x 1024:1104][pad:1280]
#define IN1_OFF   163840       // [2][64][1024]  [h0_new | h1_old]
#define IN2_OFF   294912       // [2][64][1024]  [h1_new | h2_old]
#define H2_OFF    425984       // [64][512]
#define C_OFF     458752       // [3][64][512]
#define QP_OFF    557056       // [4][64][512]
#define PC_OFF    688128       // [4][64][512]
#define MS_OFF    819200       // [4][64][2]
#define ZERO_CNT  557056

__global__ __launch_bounds__(NTHR, 2)
void sd_kernel(const float* __restrict__ tgt,  const float* __restrict__ enc,
               const int*   __restrict__ lens,
               const float* __restrict__ Wih0, const float* __restrict__ Whh0, const float* __restrict__ b0v,
               const float* __restrict__ Wih1, const float* __restrict__ Whh1, const float* __restrict__ b1v,
               const float* __restrict__ Wih2, const float* __restrict__ Whh2, const float* __restrict__ b2v,
               const float* __restrict__ Wq,   const float* __restrict__ Wfc,  const float* __restrict__ bfc,
               float* __restrict__ out, void* __restrict__ wsv)
{
  unsigned* cnt = (unsigned*)wsv;
  unsigned* gen = cnt + 1;
  float* base = (float*)((char*)wsv + 256);
  float* IN0 = base + IN0_OFF;
  float* IN1 = base + IN1_OFF;
  float* IN2 = base + IN2_OFF;
  float* H2  = base + H2_OFF;
  float* C   = base + C_OFF;
  float* QP  = base + QP_OFF;
  float* PC  = base + PC_OFF;
  float* MS  = base + MS_OFF;

  const int w = blockIdx.x, tid = threadIdx.x;
  const int s = tid & 63, r = tid >> 6;

  __shared__ __attribute__((aligned(16))) float sPart[4096];
  __shared__ __attribute__((aligned(16))) float sG4[64];
  __shared__ __attribute__((aligned(16))) float q_l[512];
  __shared__ __attribute__((aligned(16))) float s_l[128];
  __shared__ __attribute__((aligned(16))) float red[16];
  __shared__ __attribute__((aligned(16))) float ctx_l[512];

  // ---- prologue: weights -> registers (once; reused 255 steps) ----
  const int wrow  = ((r&3)<<9) + (w<<1) + (r>>2);
  const int r2p   = (tid>>3)&7;
  const int wrowb = ((r2p&3)<<9) + (w<<1) + (r2p>>2);

  float w0r[5][4], w1r[4][4], w2r[4][4];
  #pragma unroll
  for (int i=0;i<5;++i){
    #pragma unroll
    for (int j=0;j<4;++j){
      const int k = (i<<8) + (s<<2) + j;
      float v;
      if (k < 512)       v = Wih0[wrow*592 + 80 + k];        // ctx block
      else if (k < 1024) v = Whh0[(wrow<<9) + (k-512)];      // h0 block
      else if (k < 1104) v = Wih0[wrow*592 + (k-1024)];      // x block
      else               v = 0.f;                            // pad
      w0r[i][j] = v;
    }
  }
  #pragma unroll
  for (int i=0;i<4;++i){
    #pragma unroll
    for (int j=0;j<4;++j){
      const int k = (i<<8) + (s<<2) + j;
      w1r[i][j] = (k<512) ? Wih1[(wrow<<9)+k] : Whh1[(wrow<<9)+k-512];
      w2r[i][j] = (k<512) ? Wih2[(wrow<<9)+k] : Whh2[(wrow<<9)+k-512];
    }
  }
  const float br0 = b0v[wrowb], br1 = b1v[wrowb], br2 = b2v[wrowb];

  // ---- zero state each call ----
  for (int i = w*NTHR + tid; i < ZERO_CNT; i += NBLK*NTHR) base[i] = 0.f;
  gsync(cnt,gen);
  if (w >= 64 && w < 128){
    const int b = w - 64;
    if (tid < 80) IN0[b*1280 + 1024 + tid] = tgt[(b<<8)*80 + tid];   // x_0
  }
  gsync(cnt,gen);

  for (int t=0; t<255; ++t){
    const int p = t & 1, np = p ^ 1;
    float* IN0p = IN0 + p*81920;  float* IN0n = IN0 + np*81920;
    float* IN1p = IN1 + p*65536;  float* IN1n = IN1 + np*65536;
    float* IN2p = IN2 + p*65536;  float* IN2n = IN2 + np*65536;

    lstm_layer<5>(w,tid, w0r, br0, IN0p, 1280, C,         IN0n+512, 1280, IN1p, 1024, sPart, sG4);
    gsync(cnt,gen);
    lstm_layer<4>(w,tid, w1r, br1, IN1p, 1024, C+32768,   IN1n+512, 1024, IN2p, 1024, sPart, sG4);
    gsync(cnt,gen);
    lstm_layer<4>(w,tid, w2r, br2, IN2p, 1024, C+65536,   IN2n+512, 1024, H2,   512,  sPart, sG4);
    gsync(cnt,gen);

    // ---- q partials: WG (b = w&63, kq = w>>6) over k-quarter ----
    {
      const int b = w & 63, kq = w >> 6;
      const float* h2r = H2 + (b<<9) + (kq<<7);
      const float* wqp = Wq + ((size_t)(kq<<7)<<9) + tid;
      float acc = 0.f;
      #pragma unroll 4
      for (int k=0;k<128;++k) acc = fmaf(h2r[k], wqp[(size_t)k<<9], acc);
      QP[(((kq<<6)+b)<<9) + tid] = acc;
    }
    gsync(cnt,gen);

    // ---- attention A: WG (b = w&63, sq = w>>6), s-quarter flash partial ----
    {
      const int b = w & 63, sq = w >> 6, sbase = sq << 7;
      const int len = lens[b];
      q_l[tid] = QP[(b<<9)+tid] + QP[((64+b)<<9)+tid]
               + QP[((128+b)<<9)+tid] + QP[((192+b)<<9)+tid];
      __syncthreads();
      // scores: thread (sr, kc)
      {
        const int sr = tid >> 2, kc = tid & 3;
        const float* erow = enc + ((size_t)((b<<9) + sbase + sr))*512 + (kc<<7);
        const float* qv = q_l + (kc<<7);
        float a0=0.f,a1=0.f,a2=0.f,a3=0.f;
        #pragma unroll 8
        for (int m=0;m<128;m+=4){
          const float4 e4 = *(const float4*)(erow+m);
          const float4 q4 = *(const float4*)(qv+m);
          a0=fmaf(e4.x,q4.x,a0); a1=fmaf(e4.y,q4.y,a1);
          a2=fmaf(e4.z,q4.z,a2); a3=fmaf(e4.w,q4.w,a3);
        }
        float v = (a0+a1)+(a2+a3);
        v += __shfl_xor(v,1,64);
        v += __shfl_xor(v,2,64);
        if (kc==0)
          s_l[sr] = v*0.04419417382415922f + ((sbase+sr) < len ? 0.f : -1e9f);
      }
      __syncthreads();
      // local softmax over 128 scores
      float sv = (tid<128) ? s_l[tid] : -3.0e38f;
      float m = wred_max(sv);
      if ((tid&63)==0) red[tid>>6] = m;
      __syncthreads();
      float M = red[0];
      #pragma unroll
      for (int i=1;i<8;++i) M = fmaxf(M, red[i]);
      float e = (tid<128) ? __expf(sv - M) : 0.f;
      if (tid<128) s_l[tid] = e;
      float ssum = wred_sum(e);
      if ((tid&63)==0) red[8 + (tid>>6)] = ssum;
      __syncthreads();
      float S = red[8];
      #pragma unroll
      for (int i=9;i<16;++i) S += red[i];
      if (tid==0){ MS[(((sq<<6)+b)<<1)] = M; MS[(((sq<<6)+b)<<1)+1] = S; }
      // partial ctx (unnormalized, local max)
      const float* ecol = enc + ((size_t)((b<<9) + sbase))*512 + tid;
      float acc2 = 0.f;
      #pragma unroll 4
      for (int s2=0;s2<128;++s2) acc2 = fmaf(s_l[s2], ecol[(size_t)s2<<9], acc2);
      PC[(((sq<<6)+b)<<9)+tid] = acc2;
    }
    gsync(cnt,gen);

    // ---- attention B: combine + FC (WGs 0..63); x_{t+1} copy (WGs 64..127) ----
    if (w < 64){
      const int b = w;
      const float m0 = MS[(b)<<1],        S0 = MS[((b)<<1)+1];
      const float m1 = MS[(64+b)<<1],     S1 = MS[((64+b)<<1)+1];
      const float m2 = MS[(128+b)<<1],    S2 = MS[((128+b)<<1)+1];
      const float m3 = MS[(192+b)<<1],    S3 = MS[((192+b)<<1)+1];
      const float M  = fmaxf(fmaxf(m0,m1), fmaxf(m2,m3));
      const float a0=__expf(m0-M), a1=__expf(m1-M), a2=__expf(m2-M), a3=__expf(m3-M);
      const float inv = 1.f/(a0*S0 + a1*S1 + a2*S2 + a3*S3);
      const float c = (a0*PC[(b<<9)+tid]       + a1*PC[((64+b)<<9)+tid]
                     + a2*PC[((128+b)<<9)+tid] + a3*PC[((192+b)<<9)+tid]) * inv;
      IN0n[b*1280 + tid] = c;      // ctx slot for L0(t+1)
      ctx_l[tid] = c;
      __syncthreads();
      if (tid < 80){
        float acc = 0.f;
        #pragma unroll 4
        for (int e2=0;e2<512;++e2) acc = fmaf(ctx_l[e2], Wfc[e2*80+tid], acc);
        out[((size_t)b*255 + t)*80 + tid] = acc + bfc[tid];
      }
    } else if (w < 128){
      const int b = w - 64;
      if (tid < 80)
        IN0n[b*1280 + 1024 + tid] = tgt[((b<<8) + (t+1))*80 + tid];
    }
    gsync(cnt,gen);
  }
}

extern "C" void kernel_launch(void* const* d_in, const int* in_sizes, int n_in,
                              void* d_out, int out_size, void* d_ws, size_t ws_size,
                              hipStream_t stream) {
  const float* tgt  = (const float*)d_in[0];
  const float* enc  = (const float*)d_in[1];
  const int*   lens = (const int*)  d_in[2];
  const float* Wih0 = (const float*)d_in[3];
  const float* Whh0 = (const float*)d_in[4];
  const float* b0   = (const float*)d_in[5];
  const float* Wih1 = (const float*)d_in[6];
  const float* Whh1 = (const float*)d_in[7];
  const float* b1   = (const float*)d_in[8];
  const float* Wih2 = (const float*)d_in[9];
  const float* Whh2 = (const float*)d_in[10];
  const float* b2   = (const float*)d_in[11];
  const float* Wq   = (const float*)d_in[12];
  const float* Wfc  = (const float*)d_in[13];
  const float* bfc  = (const float*)d_in[14];

  hipMemsetAsync(d_ws, 0, 256, stream);   // barrier counters
  sd_kernel<<<NBLK, NTHR, 0, stream>>>(tgt, enc, lens,
                                       Wih0, Whh0, b0,
                                       Wih1, Whh1, b1,
                                       Wih2, Whh2, b2,
                                       Wq, Wfc, bfc,
                                       (float*)d_out, d_ws);
}

// Round 4
// 86158.331 us; speedup vs baseline: 2.8176x; 2.7627x over previous
//
#include <hip/hip_runtime.h>

#define NBLK 256
#define NTHR 512

// ---------------- math helpers ----------------
__device__ __forceinline__ float sigm(float x){ return 1.f/(1.f+__expf(-x)); }
__device__ __forceinline__ float tanh_(float x){ return 1.f - 2.f/(__expf(2.f*x)+1.f); }

__device__ __forceinline__ float wred_sum(float v){
  #pragma unroll
  for (int off=32; off; off>>=1) v += __shfl_xor(v, off, 64);
  return v;
}

// agent-coherent (sc1) scalar store: write-through to coherence point
__device__ __forceinline__ void st_sys(float* p, float v){
  __hip_atomic_store(p, v, __ATOMIC_RELAXED, __HIP_MEMORY_SCOPE_AGENT);
}

// two-level grid barrier; only thread 0 touches atomics; fences run on
// thread 0 only (release before signal, acquire after poll).
__device__ __forceinline__ void gsync(unsigned* bar, int w){
  __builtin_amdgcn_s_waitcnt(0);          // each wave drains its own stores
  __syncthreads();
  if (threadIdx.x == 0){
    __threadfence();                      // release: flush dirty L2 + drain
    unsigned* grp  = bar + ((w & 15) << 5);     // 128B-spread counters
    unsigned* root = bar + (16 << 5);
    unsigned* gen  = bar + (17 << 5);
    unsigned g = __hip_atomic_load(gen, __ATOMIC_RELAXED, __HIP_MEMORY_SCOPE_AGENT);
    unsigned o = __hip_atomic_fetch_add(grp, 1u, __ATOMIC_RELAXED, __HIP_MEMORY_SCOPE_AGENT);
    if (o == 15u){
      unsigned o2 = __hip_atomic_fetch_add(root, 1u, __ATOMIC_RELAXED, __HIP_MEMORY_SCOPE_AGENT);
      if (o2 == 15u){
        #pragma unroll
        for (int i=0;i<16;++i)
          __hip_atomic_store(bar + (i<<5), 0u, __ATOMIC_RELAXED, __HIP_MEMORY_SCOPE_AGENT);
        __hip_atomic_store(root, 0u, __ATOMIC_RELAXED, __HIP_MEMORY_SCOPE_AGENT);
        __hip_atomic_store(gen, g+1u, __ATOMIC_RELEASE, __HIP_MEMORY_SCOPE_AGENT); // orders resets
      } else {
        while (__hip_atomic_load(gen, __ATOMIC_RELAXED, __HIP_MEMORY_SCOPE_AGENT) == g)
          __builtin_amdgcn_s_sleep(2);
      }
    } else {
      while (__hip_atomic_load(gen, __ATOMIC_RELAXED, __HIP_MEMORY_SCOPE_AGENT) == g)
        __builtin_amdgcn_s_sleep(2);
    }
    __threadfence();                      // acquire: invalidate stale L1/L2
  }
  __syncthreads();
}

// ---------------- LSTM layer phase ----------------
// WG owns 8 rows = 2 j's x 4 gates; thread (r=tid>>6, s=tid&63) holds
// W[row][i*256 + s*4 + j] in registers. c lives in LDS (per WG, per LAYER).
template<int NI>
__device__ __forceinline__ void lstm_layer(
    int w, int tid, const float (&wt)[NI][4], float breg,
    const float* __restrict__ in, int instride,
    float* sc_c,                              // this layer's 128 cells
    float* __restrict__ dstA, int strA,
    float* __restrict__ dstB, int strB,
    float* sPart, float* sG4)
{
  const int s = tid & 63;
  const int j0 = w << 1;
  const int r  = tid >> 6;

  #pragma unroll 1
  for (int ch=0; ch<8; ++ch){
    float p[8];
    #pragma unroll
    for (int bb=0; bb<8; ++bb){
      const float* row = in + ((ch<<3)+bb)*instride + (s<<2);
      float a0=0.f,a1=0.f,a2=0.f,a3=0.f;
      #pragma unroll
      for (int i=0;i<NI;++i){
        const float4 x = *(const float4*)(row + (i<<8));
        a0 = fmaf(wt[i][0], x.x, a0);
        a1 = fmaf(wt[i][1], x.y, a1);
        a2 = fmaf(wt[i][2], x.z, a2);
        a3 = fmaf(wt[i][3], x.w, a3);
      }
      p[bb] = (a0+a1)+(a2+a3);
    }
    __syncthreads();
    #pragma unroll
    for (int bb=0; bb<8; ++bb)
      sPart[((((bb<<3)|r)<<6) | s)] = p[bb];
    __syncthreads();
    {
      const int seg = tid & 7, r2 = (tid>>3)&7, bb2 = tid>>6;
      const float* pp = sPart + (((bb2<<3)|r2)<<6) + (seg<<3);
      float v = ((pp[0]+pp[1])+(pp[2]+pp[3])) + ((pp[4]+pp[5])+(pp[6]+pp[7]));
      v += __shfl_xor(v,1,64);
      v += __shfl_xor(v,2,64);
      v += __shfl_xor(v,4,64);
      if (seg==0) sG4[(bb2<<3)|r2] = v + breg;
    }
    __syncthreads();
    if (tid < 16){
      const int bb = tid>>1, jl = tid&1;
      const int b = (ch<<3) + bb;
      const float gi = sigm (sG4[(bb<<3) + (jl<<2) + 0]);
      const float gf = sigm (sG4[(bb<<3) + (jl<<2) + 1]);
      const float gg = tanh_(sG4[(bb<<3) + (jl<<2) + 2]);
      const float go = sigm (sG4[(bb<<3) + (jl<<2) + 3]);
      const int j  = j0 + jl;
      const float cn = gf*sc_c[(ch<<4)+tid] + gi*gg;
      sc_c[(ch<<4)+tid] = cn;
      const float hn = go * tanh_(cn);
      st_sys(dstA + b*strA + j, hn);
      st_sys(dstB + b*strB + j, hn);
    }
    __syncthreads();
  }
}

// ws float offsets (after 4KB barrier area)
#define IN0_OFF   0            // [2][64][1280]  [ctx 0:512][h0 512:1024][x 1024:1104][pad:1280]
#define IN1_OFF   163840       // [2][64][1024]  [h0_new | h1_old]
#define IN2_OFF   294912       // [2][64][1024]  [h1_new | h2_old]
#define H2_OFF    425984       // [64][512]
#define QP_OFF    557056       // [4][64][512]
#define PC_OFF    688128       // [4][64][512]
#define MS_OFF    819200       // [4][64][2]
#define ZERO_CNT  458752       // IN0,IN1,IN2,H2

__global__ __launch_bounds__(NTHR, 2)
void sd_kernel(const float* __restrict__ tgt,  const float* __restrict__ enc,
               const int*   __restrict__ lens,
               const float* __restrict__ Wih0, const float* __restrict__ Whh0, const float* __restrict__ b0v,
               const float* __restrict__ Wih1, const float* __restrict__ Whh1, const float* __restrict__ b1v,
               const float* __restrict__ Wih2, const float* __restrict__ Whh2, const float* __restrict__ b2v,
               const float* __restrict__ Wq,   const float* __restrict__ Wfc,  const float* __restrict__ bfc,
               float* __restrict__ out, void* __restrict__ wsv)
{
  unsigned* bar = (unsigned*)wsv;
  float* base = (float*)((char*)wsv + 4096);
  float* IN0 = base + IN0_OFF;
  float* IN1 = base + IN1_OFF;
  float* IN2 = base + IN2_OFF;
  float* H2  = base + H2_OFF;
  float* QP  = base + QP_OFF;
  float* PC  = base + PC_OFF;
  float* MS  = base + MS_OFF;

  const int w = blockIdx.x, tid = threadIdx.x;
  const int s = tid & 63, r = tid >> 6;

  __shared__ __attribute__((aligned(16))) float sBig[4096];   // lstm partials / attn wave-ctx
  __shared__ __attribute__((aligned(16))) float sG4[64];
  __shared__ __attribute__((aligned(16))) float sVec[512];    // q_l / ctx_l
  __shared__ __attribute__((aligned(16))) float sSmall[16];
  __shared__ __attribute__((aligned(16))) float sc_c[384];    // c-cells, 128 PER LAYER

  // ---- prologue: weights -> registers ----
  const int wrow  = ((r&3)<<9) + (w<<1) + (r>>2);
  const int r2p   = (tid>>3)&7;
  const int wrowb = ((r2p&3)<<9) + (w<<1) + (r2p>>2);

  float w0r[5][4], w1r[4][4], w2r[4][4];
  #pragma unroll
  for (int i=0;i<5;++i){
    #pragma unroll
    for (int j=0;j<4;++j){
      const int k = (i<<8) + (s<<2) + j;
      float v;
      if (k < 512)       v = Wih0[wrow*592 + 80 + k];        // ctx block
      else if (k < 1024) v = Whh0[(wrow<<9) + (k-512)];      // h0 block
      else if (k < 1104) v = Wih0[wrow*592 + (k-1024)];      // x block
      else               v = 0.f;                            // pad
      w0r[i][j] = v;
    }
  }
  #pragma unroll
  for (int i=0;i<4;++i){
    #pragma unroll
    for (int j=0;j<4;++j){
      const int k = (i<<8) + (s<<2) + j;
      w1r[i][j] = (k<512) ? Wih1[(wrow<<9)+k] : Whh1[(wrow<<9)+k-512];
      w2r[i][j] = (k<512) ? Wih2[(wrow<<9)+k] : Whh2[(wrow<<9)+k-512];
    }
  }
  const float br0 = b0v[wrowb], br1 = b1v[wrowb], br2 = b2v[wrowb];

  if (tid < 384) sc_c[tid] = 0.f;
  // zero shared state (sc1 stores)
  for (int i = w*NTHR + tid; i < ZERO_CNT; i += NBLK*NTHR) st_sys(base + i, 0.f);
  gsync(bar, w);
  if (w >= 64 && w < 128){
    const int b = w - 64;
    if (tid < 80) st_sys(&IN0[b*1280 + 1024 + tid], tgt[(b<<8)*80 + tid]);   // x_0
  }
  gsync(bar, w);

  for (int t=0; t<255; ++t){
    const int p = t & 1, np = p ^ 1;
    float* IN0p = IN0 + p*81920;  float* IN0n = IN0 + np*81920;
    float* IN1p = IN1 + p*65536;  float* IN1n = IN1 + np*65536;
    float* IN2p = IN2 + p*65536;  float* IN2n = IN2 + np*65536;

    lstm_layer<5>(w,tid, w0r, br0, IN0p, 1280, sc_c,       IN0n+512, 1280, IN1p, 1024, sBig, sG4);
    gsync(bar,w);
    lstm_layer<4>(w,tid, w1r, br1, IN1p, 1024, sc_c+128,   IN1n+512, 1024, IN2p, 1024, sBig, sG4);
    gsync(bar,w);
    lstm_layer<4>(w,tid, w2r, br2, IN2p, 1024, sc_c+256,   IN2n+512, 1024, H2,   512,  sBig, sG4);
    gsync(bar,w);

    // ---- q partials: WG (b = w&63, kq = w>>6) over k-quarter ----
    {
      const int b = w & 63, kq = w >> 6;
      const float* h2r = H2 + (b<<9) + (kq<<7);
      const float* wqp = Wq + ((size_t)(kq<<7)<<9) + tid;
      float acc = 0.f;
      #pragma unroll 4
      for (int k=0;k<128;++k) acc = fmaf(h2r[k], wqp[(size_t)k<<9], acc);
      st_sys(&QP[(((kq<<6)+b)<<9) + tid], acc);
    }
    gsync(bar,w);

    // ---- attention A: WG (b, sq): online-softmax over 128 enc rows ----
    {
      const int b = w & 63, sq = w >> 6;
      const int len  = lens[b];
      const int lane = tid & 63, wv = tid >> 6;
      sVec[tid] = QP[(b<<9)+tid] + QP[((64+b)<<9)+tid]
                + QP[((128+b)<<9)+tid] + QP[((192+b)<<9)+tid];
      __syncthreads();
      const float4 qA = *(const float4*)(sVec + (lane<<3));
      const float4 qB = *(const float4*)(sVec + (lane<<3) + 4);
      float mr = -3.0e38f, lr = 0.f;
      float c0=0,c1=0,c2=0,c3=0,c4=0,c5=0,c6=0,c7=0;
      const float scale = 0.04419417382415922f;   // 1/sqrt(512)
      #pragma unroll 1
      for (int rr=0; rr<16; ++rr){
        const int srow = (sq<<7) + (wv<<4) + rr;     // wave-uniform
        if (srow >= len) break;                       // rows monotonic
        const float* ep = enc + (((size_t)(b<<9)+srow)<<9) + (lane<<3);
        const float4 e0 = *(const float4*)(ep);
        const float4 e1 = *(const float4*)(ep+4);
        float d0 = qA.x*e0.x, d1 = qA.y*e0.y, d2 = qA.z*e0.z, d3 = qA.w*e0.w;
        d0 = fmaf(qB.x, e1.x, d0); d1 = fmaf(qB.y, e1.y, d1);
        d2 = fmaf(qB.z, e1.z, d2); d3 = fmaf(qB.w, e1.w, d3);
        float d = wred_sum((d0+d1)+(d2+d3));
        const float sc = d*scale;
        const float mn = fmaxf(mr, sc);
        const float sf = __expf(mr - mn);
        const float pe = __expf(sc - mn);
        lr = fmaf(lr, sf, pe);
        c0 = fmaf(c0, sf, pe*e0.x); c1 = fmaf(c1, sf, pe*e0.y);
        c2 = fmaf(c2, sf, pe*e0.z); c3 = fmaf(c3, sf, pe*e0.w);
        c4 = fmaf(c4, sf, pe*e1.x); c5 = fmaf(c5, sf, pe*e1.y);
        c6 = fmaf(c6, sf, pe*e1.z); c7 = fmaf(c7, sf, pe*e1.w);
        mr = mn;
      }
      if (lane==0){ sSmall[wv] = mr; sSmall[8+wv] = lr; }
      {
        float4 v0 = {c0,c1,c2,c3}, v1 = {c4,c5,c6,c7};
        *(float4*)(sBig + (wv<<9) + (lane<<3))     = v0;
        *(float4*)(sBig + (wv<<9) + (lane<<3) + 4) = v1;
      }
      __syncthreads();
      float M = sSmall[0];
      #pragma unroll
      for (int i=1;i<8;++i) M = fmaxf(M, sSmall[i]);
      float L = 0.f, acc = 0.f;
      #pragma unroll
      for (int i=0;i<8;++i){
        const float A = __expf(sSmall[i]-M);
        L   = fmaf(A, sSmall[8+i], L);
        acc = fmaf(A, sBig[(i<<9)+tid], acc);
      }
      st_sys(&PC[(((sq<<6)+b)<<9)+tid], acc);
      if (tid==0){
        st_sys(&MS[(((sq<<6)+b)<<1)],   M);
        st_sys(&MS[(((sq<<6)+b)<<1)+1], L);
      }
    }
    gsync(bar,w);

    // ---- attention B: combine + FC (WGs 0..63); x_{t+1} copy (WGs 64..127) ----
    if (w < 64){
      const int b = w;
      const float m0 = MS[(b)<<1],        S0 = MS[((b)<<1)+1];
      const float m1 = MS[(64+b)<<1],     S1 = MS[((64+b)<<1)+1];
      const float m2 = MS[(128+b)<<1],    S2 = MS[((128+b)<<1)+1];
      const float m3 = MS[(192+b)<<1],    S3 = MS[((192+b)<<1)+1];
      const float M  = fmaxf(fmaxf(m0,m1), fmaxf(m2,m3));
      const float a0=__expf(m0-M), a1=__expf(m1-M), a2=__expf(m2-M), a3=__expf(m3-M);
      const float inv = 1.f/(a0*S0 + a1*S1 + a2*S2 + a3*S3);
      const float c = (a0*PC[(b<<9)+tid]       + a1*PC[((64+b)<<9)+tid]
                     + a2*PC[((128+b)<<9)+tid] + a3*PC[((192+b)<<9)+tid]) * inv;
      st_sys(&IN0n[b*1280 + tid], c);      // ctx slot for L0(t+1)
      sVec[tid] = c;
      __syncthreads();
      if (tid < 80){
        float acc = 0.f;
        #pragma unroll 4
        for (int e2=0;e2<512;++e2) acc = fmaf(sVec[e2], Wfc[e2*80+tid], acc);
        st_sys(&out[((size_t)b*255 + t)*80 + tid], acc + bfc[tid]);
      }
    } else if (w < 128){
      const int b = w - 64;
      if (tid < 80)
        st_sys(&IN0n[b*1280 + 1024 + tid], tgt[((b<<8) + (t+1))*80 + tid]);
    }
    gsync(bar,w);
  }
}

extern "C" void kernel_launch(void* const* d_in, const int* in_sizes, int n_in,
                              void* d_out, int out_size, void* d_ws, size_t ws_size,
                              hipStream_t stream) {
  const float* tgt  = (const float*)d_in[0];
  const float* enc  = (const float*)d_in[1];
  const int*   lens = (const int*)  d_in[2];
  const float* Wih0 = (const float*)d_in[3];
  const float* Whh0 = (const float*)d_in[4];
  const float* b0   = (const float*)d_in[5];
  const float* Wih1 = (const float*)d_in[6];
  const float* Whh1 = (const float*)d_in[7];
  const float* b1   = (const float*)d_in[8];
  const float* Wih2 = (const float*)d_in[9];
  const float* Whh2 = (const float*)d_in[10];
  const float* b2   = (const float*)d_in[11];
  const float* Wq   = (const float*)d_in[12];
  const float* Wfc  = (const float*)d_in[13];
  const float* bfc  = (const float*)d_in[14];

  hipMemsetAsync(d_ws, 0, 4096, stream);   // barrier counters
  sd_kernel<<<NBLK, NTHR, 0, stream>>>(tgt, enc, lens,
                                       Wih0, Whh0, b0,
                                       Wih1, Whh1, b1,
                                       Wih2, Whh2, b2,
                                       Wq, Wfc, bfc,
                                       (float*)d_out, d_ws);
}

// Round 5
// 34166.534 us; speedup vs baseline: 7.1052x; 2.5217x over previous
//
#include <hip/hip_runtime.h>

#define NBLK 256
#define NTHR 512

// ---------------- math helpers ----------------
__device__ __forceinline__ float sigm(float x){ return 1.f/(1.f+__expf(-x)); }
__device__ __forceinline__ float tanh_(float x){ return 1.f - 2.f/(__expf(2.f*x)+1.f); }

__device__ __forceinline__ float wred_sum(float v){
  #pragma unroll
  for (int off=32; off; off>>=1) v += __shfl_xor(v, off, 64);
  return v;
}

// agent-coherent (sc1) store/load: write-through / L2-bypass read.
// ALL cross-WG state goes through these; read-only inputs use normal
// cached loads and are never invalidated (no threadfence in this kernel).
__device__ __forceinline__ void st_sys(float* p, float v){
  __hip_atomic_store(p, v, __ATOMIC_RELAXED, __HIP_MEMORY_SCOPE_AGENT);
}
__device__ __forceinline__ float ald(const float* p){
  return __hip_atomic_load(p, __ATOMIC_RELAXED, __HIP_MEMORY_SCOPE_AGENT);
}

// two-level grid barrier; no cache maintenance. __syncthreads drains vmcnt
// (compiler emits s_waitcnt vmcnt(0) before s_barrier), so all waves' sc1
// stores are at the coherence point before thread 0 signals.
__device__ __forceinline__ void gsync(unsigned* bar, int w){
  __builtin_amdgcn_s_waitcnt(0);
  __syncthreads();
  if (threadIdx.x == 0){
    unsigned* grp  = bar + ((w & 15) << 5);     // 128B-spread counters
    unsigned* root = bar + (16 << 5);
    unsigned* gen  = bar + (17 << 5);
    unsigned g = __hip_atomic_load(gen, __ATOMIC_RELAXED, __HIP_MEMORY_SCOPE_AGENT);
    unsigned o = __hip_atomic_fetch_add(grp, 1u, __ATOMIC_RELAXED, __HIP_MEMORY_SCOPE_AGENT);
    if (o == 15u){
      unsigned o2 = __hip_atomic_fetch_add(root, 1u, __ATOMIC_RELAXED, __HIP_MEMORY_SCOPE_AGENT);
      if (o2 == 15u){
        #pragma unroll
        for (int i=0;i<16;++i)
          __hip_atomic_store(bar + (i<<5), 0u, __ATOMIC_RELAXED, __HIP_MEMORY_SCOPE_AGENT);
        __hip_atomic_store(root, 0u, __ATOMIC_RELAXED, __HIP_MEMORY_SCOPE_AGENT);
        __hip_atomic_store(gen, g+1u, __ATOMIC_RELEASE, __HIP_MEMORY_SCOPE_AGENT);
      } else {
        while (__hip_atomic_load(gen, __ATOMIC_RELAXED, __HIP_MEMORY_SCOPE_AGENT) == g)
          __builtin_amdgcn_s_sleep(2);
      }
    } else {
      while (__hip_atomic_load(gen, __ATOMIC_RELAXED, __HIP_MEMORY_SCOPE_AGENT) == g)
        __builtin_amdgcn_s_sleep(2);
    }
  }
  __syncthreads();
}

// ---------------- LSTM layer (b-chunked LDS staging) ----------------
// WG owns 8 rows = 2 j x 4 gates; thread (r=tid>>6, s=tid&63) holds
// W[row][i*256 + s*4 + j] in registers. Per 8-batch chunk: input staged
// once into LDS via sc1 loads (double-buffered), 8x reuse from LDS.

template<int NI>
__device__ __forceinline__ void loadch(const float* __restrict__ in, int ch, int tid,
                                       float (&v)[NI][4]){
  const float* cb = in + ch*(NI<<11);          // 8 rows * NI*256 floats
  #pragma unroll
  for (int i=0;i<NI;++i){
    const int f = ((i<<9)+tid)<<2;
    #pragma unroll
    for (int j=0;j<4;++j) v[i][j] = ald(cb + f + j);
  }
}

template<int NI>
__device__ __forceinline__ void stw(float* S, int tid, const float (&v)[NI][4]){
  #pragma unroll
  for (int i=0;i<NI;++i){
    float4 x = {v[i][0],v[i][1],v[i][2],v[i][3]};
    *(float4*)(S + (((i<<9)+tid)<<2)) = x;
  }
}

template<int NI>
__device__ __forceinline__ void cchunk(
    const float* S, int ch, int tid, int s, int r,
    const float (&wt)[NI][4], float breg,
    float* sc_c, float* sPart, float* sG4,
    int j0, float* __restrict__ dstA, int strA,
    float* __restrict__ dstB, int strB)
{
  float p[8];
  #pragma unroll
  for (int bb=0; bb<8; ++bb){
    const float* row = S + bb*(NI<<8) + (s<<2);
    float a0=0.f,a1=0.f,a2=0.f,a3=0.f;
    #pragma unroll
    for (int i=0;i<NI;++i){
      const float4 x = *(const float4*)(row + (i<<8));
      a0 = fmaf(wt[i][0], x.x, a0);
      a1 = fmaf(wt[i][1], x.y, a1);
      a2 = fmaf(wt[i][2], x.z, a2);
      a3 = fmaf(wt[i][3], x.w, a3);
    }
    p[bb] = (a0+a1)+(a2+a3);
  }
  #pragma unroll
  for (int bb=0; bb<8; ++bb)
    sPart[((((bb<<3)|r)<<6) | s)] = p[bb];
  __syncthreads();
  {
    const int seg = tid & 7, r2 = (tid>>3)&7, bb2 = tid>>6;
    const float* pp = sPart + (((bb2<<3)|r2)<<6) + (seg<<3);
    float v = ((pp[0]+pp[1])+(pp[2]+pp[3])) + ((pp[4]+pp[5])+(pp[6]+pp[7]));
    v += __shfl_xor(v,1,64);
    v += __shfl_xor(v,2,64);
    v += __shfl_xor(v,4,64);
    if (seg==0) sG4[(bb2<<3)|r2] = v + breg;
  }
  __syncthreads();
  if (tid < 16){
    const int bb = tid>>1, jl = tid&1;
    const int b = (ch<<3) + bb;
    const float gi = sigm (sG4[(bb<<3) + (jl<<2) + 0]);
    const float gf = sigm (sG4[(bb<<3) + (jl<<2) + 1]);
    const float gg = tanh_(sG4[(bb<<3) + (jl<<2) + 2]);
    const float go = sigm (sG4[(bb<<3) + (jl<<2) + 3]);
    const int j  = j0 + jl;
    const float cn = gf*sc_c[(ch<<4)+tid] + gi*gg;
    sc_c[(ch<<4)+tid] = cn;
    const float hn = go * tanh_(cn);
    st_sys(dstA + b*strA + j, hn);
    st_sys(dstB + b*strB + j, hn);
  }
}

template<int NI>
__device__ __forceinline__ void lstm_layer(
    int w, int tid, const float (&wt)[NI][4], float breg,
    const float* __restrict__ in, float* sc_c,
    float* __restrict__ dstA, int strA,
    float* __restrict__ dstB, int strB,
    float* S0, float* S1, float* sPart, float* sG4)
{
  const int s = tid & 63, r = tid >> 6, j0 = w << 1;
  float vA[NI][4], vB[NI][4];
  loadch<NI>(in, 0, tid, vA);
  #pragma unroll 1
  for (int ch=0; ch<8; ch+=2){
    stw<NI>(S0, tid, vA);
    loadch<NI>(in, ch+1, tid, vB);
    __syncthreads();                                 // stage0 visible, sPart free
    cchunk<NI>(S0, ch,   tid,s,r, wt,breg, sc_c,sPart,sG4, j0, dstA,strA, dstB,strB);
    stw<NI>(S1, tid, vB);
    if (ch+2 < 8) loadch<NI>(in, ch+2, tid, vA);
    __syncthreads();                                 // stage1 visible
    cchunk<NI>(S1, ch+1, tid,s,r, wt,breg, sc_c,sPart,sG4, j0, dstA,strA, dstB,strB);
  }
}

// ws float offsets (after 4KB barrier area)
#define IN0_OFF   0            // [2][64][1280]  [ctx 0:512][h0 512:1024][x 1024:1104][pad:1280]
#define IN1_OFF   163840       // [2][64][1024]  [h0_new | h1_old]
#define IN2_OFF   294912       // [2][64][1024]  [h1_new | h2_old]
#define H2_OFF    425984       // [64][512]
#define QP_OFF    557056       // [4][64][512]
#define PC_OFF    688128       // [4][64][512]
#define MS_OFF    819200       // [4][64][2]
#define ZERO_CNT  458752       // IN0,IN1,IN2,H2

__global__ __launch_bounds__(NTHR, 2)
void sd_kernel(const float* __restrict__ tgt,  const float* __restrict__ enc,
               const int*   __restrict__ lens,
               const float* __restrict__ Wih0, const float* __restrict__ Whh0, const float* __restrict__ b0v,
               const float* __restrict__ Wih1, const float* __restrict__ Whh1, const float* __restrict__ b1v,
               const float* __restrict__ Wih2, const float* __restrict__ Whh2, const float* __restrict__ b2v,
               const float* __restrict__ Wq,   const float* __restrict__ Wfc,  const float* __restrict__ bfc,
               float* __restrict__ out, void* __restrict__ wsv)
{
  unsigned* bar = (unsigned*)wsv;
  float* base = (float*)((char*)wsv + 4096);
  float* IN0 = base + IN0_OFF;
  float* IN1 = base + IN1_OFF;
  float* IN2 = base + IN2_OFF;
  float* H2  = base + H2_OFF;
  float* QP  = base + QP_OFF;
  float* PC  = base + PC_OFF;
  float* MS  = base + MS_OFF;

  const int w = blockIdx.x, tid = threadIdx.x;
  const int s = tid & 63, r = tid >> 6;

  __shared__ __attribute__((aligned(16))) float sStage0[10240];  // chunk stage buf A
  __shared__ __attribute__((aligned(16))) float sStage1[10240];  // chunk stage buf B
  __shared__ __attribute__((aligned(16))) float sBig[4096];      // lstm partials / attn wave-ctx
  __shared__ __attribute__((aligned(16))) float sG4[64];
  __shared__ __attribute__((aligned(16))) float sVec[512];       // h2q / q_l / ctx_l
  __shared__ __attribute__((aligned(16))) float sSmall[16];
  __shared__ __attribute__((aligned(16))) float sc_c[384];       // c-cells, 128 per layer

  // ---- prologue: weights -> registers (normal cached loads; read-only) ----
  const int wrow  = ((r&3)<<9) + (w<<1) + (r>>2);
  const int r2p   = (tid>>3)&7;
  const int wrowb = ((r2p&3)<<9) + (w<<1) + (r2p>>2);

  float w0r[5][4], w1r[4][4], w2r[4][4];
  #pragma unroll
  for (int i=0;i<5;++i){
    #pragma unroll
    for (int j=0;j<4;++j){
      const int k = (i<<8) + (s<<2) + j;
      float v;
      if (k < 512)       v = Wih0[wrow*592 + 80 + k];        // ctx block
      else if (k < 1024) v = Whh0[(wrow<<9) + (k-512)];      // h0 block
      else if (k < 1104) v = Wih0[wrow*592 + (k-1024)];      // x block
      else               v = 0.f;                            // pad
      w0r[i][j] = v;
    }
  }
  #pragma unroll
  for (int i=0;i<4;++i){
    #pragma unroll
    for (int j=0;j<4;++j){
      const int k = (i<<8) + (s<<2) + j;
      w1r[i][j] = (k<512) ? Wih1[(wrow<<9)+k] : Whh1[(wrow<<9)+k-512];
      w2r[i][j] = (k<512) ? Wih2[(wrow<<9)+k] : Whh2[(wrow<<9)+k-512];
    }
  }
  const float br0 = b0v[wrowb], br1 = b1v[wrowb], br2 = b2v[wrowb];

  if (tid < 384) sc_c[tid] = 0.f;
  for (int i = w*NTHR + tid; i < ZERO_CNT; i += NBLK*NTHR) st_sys(base + i, 0.f);
  gsync(bar, w);
  if (w >= 64 && w < 128){
    const int b = w - 64;
    if (tid < 80) st_sys(&IN0[b*1280 + 1024 + tid], tgt[(b<<8)*80 + tid]);   // x_0
  }
  gsync(bar, w);

  for (int t=0; t<255; ++t){
    const int p = t & 1, np = p ^ 1;
    float* IN0p = IN0 + p*81920;  float* IN0n = IN0 + np*81920;
    float* IN1p = IN1 + p*65536;  float* IN1n = IN1 + np*65536;
    float* IN2p = IN2 + p*65536;  float* IN2n = IN2 + np*65536;

    lstm_layer<5>(w,tid, w0r, br0, IN0p, sc_c,     IN0n+512, 1280, IN1p, 1024, sStage0,sStage1, sBig, sG4);
    gsync(bar,w);
    lstm_layer<4>(w,tid, w1r, br1, IN1p, sc_c+128, IN1n+512, 1024, IN2p, 1024, sStage0,sStage1, sBig, sG4);
    gsync(bar,w);
    lstm_layer<4>(w,tid, w2r, br2, IN2p, sc_c+256, IN2n+512, 1024, H2,   512,  sStage0,sStage1, sBig, sG4);
    gsync(bar,w);

    // ---- q partials: WG (b = w&63, kq = w>>6) over k-quarter ----
    {
      const int b = w & 63, kq = w >> 6;
      if (tid < 128) sVec[tid] = ald(&H2[(b<<9) + (kq<<7) + tid]);
      __syncthreads();
      const float* wqp = Wq + ((size_t)(kq<<7)<<9) + tid;     // normal cached (L2-hot)
      float acc = 0.f;
      #pragma unroll 4
      for (int k=0;k<128;++k) acc = fmaf(sVec[k], wqp[(size_t)k<<9], acc);
      st_sys(&QP[(((kq<<6)+b)<<9) + tid], acc);
    }
    gsync(bar,w);

    // ---- attention A: WG (b, sq): online-softmax over 128 enc rows ----
    {
      const int b = w & 63, sq = w >> 6;
      const int len  = lens[b];
      const int lane = tid & 63, wv = tid >> 6;
      sVec[tid] = ald(&QP[(b<<9)+tid]) + ald(&QP[((64+b)<<9)+tid])
                + ald(&QP[((128+b)<<9)+tid]) + ald(&QP[((192+b)<<9)+tid]);
      __syncthreads();
      const float4 qA = *(const float4*)(sVec + (lane<<3));
      const float4 qB = *(const float4*)(sVec + (lane<<3) + 4);
      float mr = -3.0e38f, lr = 0.f;
      float c0=0,c1=0,c2=0,c3=0,c4=0,c5=0,c6=0,c7=0;
      const float scale = 0.04419417382415922f;   // 1/sqrt(512)
      #pragma unroll 1
      for (int rr=0; rr<16; ++rr){
        const int srow = (sq<<7) + (wv<<4) + rr;     // wave-uniform
        if (srow >= len) break;                       // rows monotonic
        const float* ep = enc + (((size_t)(b<<9)+srow)<<9) + (lane<<3);  // normal cached
        const float4 e0 = *(const float4*)(ep);
        const float4 e1 = *(const float4*)(ep+4);
        float d0 = qA.x*e0.x, d1 = qA.y*e0.y, d2 = qA.z*e0.z, d3 = qA.w*e0.w;
        d0 = fmaf(qB.x, e1.x, d0); d1 = fmaf(qB.y, e1.y, d1);
        d2 = fmaf(qB.z, e1.z, d2); d3 = fmaf(qB.w, e1.w, d3);
        float d = wred_sum((d0+d1)+(d2+d3));
        const float sc = d*scale;
        const float mn = fmaxf(mr, sc);
        const float sf = __expf(mr - mn);
        const float pe = __expf(sc - mn);
        lr = fmaf(lr, sf, pe);
        c0 = fmaf(c0, sf, pe*e0.x); c1 = fmaf(c1, sf, pe*e0.y);
        c2 = fmaf(c2, sf, pe*e0.z); c3 = fmaf(c3, sf, pe*e0.w);
        c4 = fmaf(c4, sf, pe*e1.x); c5 = fmaf(c5, sf, pe*e1.y);
        c6 = fmaf(c6, sf, pe*e1.z); c7 = fmaf(c7, sf, pe*e1.w);
        mr = mn;
      }
      if (lane==0){ sSmall[wv] = mr; sSmall[8+wv] = lr; }
      {
        float4 v0 = {c0,c1,c2,c3}, v1 = {c4,c5,c6,c7};
        *(float4*)(sBig + (wv<<9) + (lane<<3))     = v0;
        *(float4*)(sBig + (wv<<9) + (lane<<3) + 4) = v1;
      }
      __syncthreads();
      float M = sSmall[0];
      #pragma unroll
      for (int i=1;i<8;++i) M = fmaxf(M, sSmall[i]);
      float L = 0.f, acc = 0.f;
      #pragma unroll
      for (int i=0;i<8;++i){
        const float A = __expf(sSmall[i]-M);
        L   = fmaf(A, sSmall[8+i], L);
        acc = fmaf(A, sBig[(i<<9)+tid], acc);
      }
      st_sys(&PC[(((sq<<6)+b)<<9)+tid], acc);
      if (tid==0){
        st_sys(&MS[(((sq<<6)+b)<<1)],   M);
        st_sys(&MS[(((sq<<6)+b)<<1)+1], L);
      }
    }
    gsync(bar,w);

    // ---- attention B: combine + FC (WGs 0..63); x_{t+1} copy (WGs 64..127) ----
    if (w < 64){
      const int b = w;
      const float m0 = ald(&MS[(b)<<1]),      S0 = ald(&MS[((b)<<1)+1]);
      const float m1 = ald(&MS[(64+b)<<1]),   S1 = ald(&MS[((64+b)<<1)+1]);
      const float m2 = ald(&MS[(128+b)<<1]),  S2 = ald(&MS[((128+b)<<1)+1]);
      const float m3 = ald(&MS[(192+b)<<1]),  S3 = ald(&MS[((192+b)<<1)+1]);
      const float M  = fmaxf(fmaxf(m0,m1), fmaxf(m2,m3));
      const float a0=__expf(m0-M), a1=__expf(m1-M), a2=__expf(m2-M), a3=__expf(m3-M);
      const float inv = 1.f/(a0*S0 + a1*S1 + a2*S2 + a3*S3);
      const float c = (a0*ald(&PC[(b<<9)+tid])       + a1*ald(&PC[((64+b)<<9)+tid])
                     + a2*ald(&PC[((128+b)<<9)+tid]) + a3*ald(&PC[((192+b)<<9)+tid])) * inv;
      st_sys(&IN0n[b*1280 + tid], c);      // ctx slot for L0(t+1)
      sVec[tid] = c;
      __syncthreads();
      if (tid < 80){
        float acc = 0.f;
        #pragma unroll 4
        for (int e2=0;e2<512;++e2) acc = fmaf(sVec[e2], Wfc[e2*80+tid], acc);  // normal cached
        out[((size_t)b*255 + t)*80 + tid] = acc + bfc[tid];
      }
    } else if (w < 128){
      const int b = w - 64;
      if (tid < 80)
        st_sys(&IN0n[b*1280 + 1024 + tid], tgt[((b<<8) + (t+1))*80 + tid]);
    }
    gsync(bar,w);
  }
}

extern "C" void kernel_launch(void* const* d_in, const int* in_sizes, int n_in,
                              void* d_out, int out_size, void* d_ws, size_t ws_size,
                              hipStream_t stream) {
  const float* tgt  = (const float*)d_in[0];
  const float* enc  = (const float*)d_in[1];
  const int*   lens = (const int*)  d_in[2];
  const float* Wih0 = (const float*)d_in[3];
  const float* Whh0 = (const float*)d_in[4];
  const float* b0   = (const float*)d_in[5];
  const float* Wih1 = (const float*)d_in[6];
  const float* Whh1 = (const float*)d_in[7];
  const float* b1   = (const float*)d_in[8];
  const float* Wih2 = (const float*)d_in[9];
  const float* Whh2 = (const float*)d_in[10];
  const float* b2   = (const float*)d_in[11];
  const float* Wq   = (const float*)d_in[12];
  const float* Wfc  = (const float*)d_in[13];
  const float* bfc  = (const float*)d_in[14];

  hipMemsetAsync(d_ws, 0, 4096, stream);   // barrier counters
  sd_kernel<<<NBLK, NTHR, 0, stream>>>(tgt, enc, lens,
                                       Wih0, Whh0, b0,
                                       Wih1, Whh1, b1,
                                       Wih2, Whh2, b2,
                                       Wq, Wfc, bfc,
                                       (float*)d_out, d_ws);
}